// Round 5
// baseline (3384.759 us; speedup 1.0000x reference)
//
#include <hip/hip_runtime.h>
#include <float.h>

#define M_TOK 16384   // B*T
#define DIM   256
#define NCODE 1024
#define NQ    8
#define FEAT  756

__device__ __forceinline__ float fm(float a, float b) { return __fmul_rn(a, b); }
__device__ __forceinline__ float fa(float a, float b) { return __fadd_rn(a, b); }
__device__ __forceinline__ float fs(float a, float b) { return __fsub_rn(a, b); }

// ---- numpy pairwise_sum (SSE2-npyv) of squares, n=128 block ----
// r[j] (vec4) init from first 32 elems; 3 more rounds; combine
// ((r0+r1)+(r2+r3))+((r4+r5)+(r6+r7)); hsum (l0+l2)+(l1+l3).
__device__ float pairwise128_sq(const float* a) {
  float V[8][4];
#pragma unroll
  for (int j = 0; j < 8; ++j)
#pragma unroll
    for (int l = 0; l < 4; ++l) { float x = a[4 * j + l]; V[j][l] = fm(x, x); }
#pragma unroll
  for (int t = 1; t < 4; ++t)
#pragma unroll
    for (int j = 0; j < 8; ++j)
#pragma unroll
      for (int l = 0; l < 4; ++l) {
        float x = a[32 * t + 4 * j + l];
        V[j][l] = fa(V[j][l], fm(x, x));
      }
  float W[4];
#pragma unroll
  for (int l = 0; l < 4; ++l) {
    float p01 = fa(V[0][l], V[1][l]), p23 = fa(V[2][l], V[3][l]);
    float p45 = fa(V[4][l], V[5][l]), p67 = fa(V[6][l], V[7][l]);
    W[l] = fa(fa(p01, p23), fa(p45, p67));
  }
  return fa(fa(W[0], W[2]), fa(W[1], W[3]));
}
__device__ float pairwise256_sq(const float* a) {
  return fa(pairwise128_sq(a), pairwise128_sq(a + 128));  // n2 = 128 split
}

// ---- numpy einsum contig_two f32: single 4-lane acc, seq mul+add, hsum (0+2)+(1+3) ----
__device__ float dot256_np(const float* __restrict__ r, const float* __restrict__ c) {
  float L0 = 0.f, L1 = 0.f, L2 = 0.f, L3 = 0.f;
#pragma unroll 16
  for (int t = 0; t < 64; ++t) {
    float4 rv = *reinterpret_cast<const float4*>(r + 4 * t);
    float4 cv = *reinterpret_cast<const float4*>(c + 4 * t);
    L0 = fa(L0, fm(rv.x, cv.x));
    L1 = fa(L1, fm(rv.y, cv.y));
    L2 = fa(L2, fm(rv.z, cv.z));
    L3 = fa(L3, fm(rv.w, cv.w));
  }
  return fa(fa(L0, L2), fa(L1, L3));
}

// ---- z: einsum generic path — strictly sequential scalar mul+add over f ----
__global__ __launch_bounds__(256) void k_z(const float* __restrict__ in,
                                           const float* __restrict__ w_in,
                                           float* __restrict__ residual) {
  const int m = blockIdx.x;
  __shared__ float xs[FEAT];
  for (int i = threadIdx.x; i < FEAT; i += 256) xs[i] = in[(size_t)m * FEAT + i];
  __syncthreads();
  const int d = threadIdx.x;
  float acc = 0.f;
  for (int F = 0; F < FEAT; ++F) {                 // einsum feature axis, ascending
    int c = F / 252, fh = F - c * 252;             // x[m][F] = inputs[m][fh][c]
    acc = fa(acc, fm(xs[fh * 3 + c], w_in[(size_t)F * DIM + d]));
  }
  residual[(size_t)m * DIM + d] = acc;
}

// ---- codebook row norms via numpy pairwise ----
__global__ __launch_bounds__(256) void k_cbnorm(const float* __restrict__ cb,
                                                float* __restrict__ cbn) {
  int row = blockIdx.x * 256 + threadIdx.x;
  if (row >= NQ * NCODE) return;
  cbn[row] = pairwise256_sq(&cb[(size_t)row * DIM]);
}

// ---- one residual-VQ step, numpy-f32-exact ----
__global__ __launch_bounds__(256) void k_vq(const float* __restrict__ cb,
                                            const float* __restrict__ cbn,
                                            float* __restrict__ residual,
                                            float* __restrict__ allq,
                                            float* __restrict__ idxout, int q) {
  __shared__ __align__(16) float rs[16][260];
  __shared__ __align__(16) float cs[16][260];
  __shared__ float cbn_s[NCODE];
  __shared__ float t1_s[16];
  __shared__ int idx_s[16];
  const int m0 = blockIdx.x * 16;
  const int tid = threadIdx.x;
  const int cc = tid & 15, tt = tid >> 4;
  const float* cbq = cb + (size_t)q * NCODE * DIM;

#pragma unroll
  for (int k = 0; k < 4; ++k) {                    // stage 16 residual rows
    int li = tid + k * 256, row = li >> 6, c4 = li & 63;
    float4 v = *reinterpret_cast<const float4*>(&residual[(size_t)(m0 + row) * DIM + c4 * 4]);
    rs[row][c4 * 4 + 0] = v.x; rs[row][c4 * 4 + 1] = v.y;
    rs[row][c4 * 4 + 2] = v.z; rs[row][c4 * 4 + 3] = v.w;
  }
  for (int i = tid; i < NCODE; i += 256) cbn_s[i] = cbn[q * NCODE + i];
  __syncthreads();
  if (tid < 16) t1_s[tid] = pairwise256_sq(&rs[tid][0]);   // np.sum(r*r, -1) pairwise
  __syncthreads();

  float best = FLT_MAX; int bidx = 0;
  for (int ct = 0; ct < 64; ++ct) {
#pragma unroll
    for (int k = 0; k < 4; ++k) {                  // stage 16 code rows
      int li = tid + k * 256, row = li >> 6, c4 = li & 63;
      float4 v = *reinterpret_cast<const float4*>(&cbq[(size_t)(ct * 16 + row) * DIM + c4 * 4]);
      cs[row][c4 * 4 + 0] = v.x; cs[row][c4 * 4 + 1] = v.y;
      cs[row][c4 * 4 + 2] = v.z; cs[row][c4 * 4 + 3] = v.w;
    }
    __syncthreads();
    const float e = dot256_np(&rs[tt][0], &cs[cc][0]);
    const int code = ct * 16 + cc;
    // d = fl( fl(t1 - fl(2*E)) + t3 )
    const float dist = fa(fs(t1_s[tt], fa(e, e)), cbn_s[code]);
    if (dist < best) { best = dist; bidx = code; } // per-thread codes ascending
    __syncthreads();
  }
  // reduce across the 16 cc-lanes of each token; first-index tie-break
#pragma unroll
  for (int off = 8; off >= 1; off >>= 1) {
    float ov = __shfl_xor(best, off, 64);
    int oi = __shfl_xor(bidx, off, 64);
    if (ov < best || (ov == best && oi < bidx)) { best = ov; bidx = oi; }
  }
  if (cc == 0) idx_s[tt] = bidx;
  __syncthreads();
  const int ci = idx_s[tt];
  const float* crow = &cbq[(size_t)ci * DIM];
#pragma unroll
  for (int j = 0; j < 16; ++j) {
    int dd = j * 16 + cc;                          // lanes cover consecutive dims
    float cv = crow[dd];
    residual[(size_t)(m0 + tt) * DIM + dd] = fs(rs[tt][dd], cv);  // f32 step, as np
    allq[((size_t)q * M_TOK + m0 + tt) * DIM + dd] = cv;
  }
  if (cc == 0) idxout[(size_t)(m0 + tt) * NQ + q] = (float)ci;
}

// ---- quantized = relu( (sum_q allq[q]) @ w_out ) — loose tolerance, plain f32 ----
__global__ __launch_bounds__(256) void k_out(const float* __restrict__ allq,
                                             const float* __restrict__ w_out,
                                             float* __restrict__ C) {
  const int m = blockIdx.x;
  __shared__ float qs[DIM];
  float s = 0.f;
  for (int qq = 0; qq < NQ; ++qq)
    s += allq[((size_t)qq * M_TOK + m) * DIM + threadIdx.x];
  qs[threadIdx.x] = s;
  __syncthreads();
  for (int j = threadIdx.x; j < FEAT; j += 256) {
    float acc = 0.f;
    for (int d = 0; d < DIM; ++d) acc += qs[d] * w_out[(size_t)d * FEAT + j];
    C[(size_t)m * FEAT + j] = fmaxf(acc, 0.f);
  }
}

extern "C" void kernel_launch(void* const* d_in, const int* in_sizes, int n_in,
                              void* d_out, int out_size, void* d_ws, size_t ws_size,
                              hipStream_t stream) {
  // resolve by size; the two equal-size weights keep dict order (w_in first)
  int i_inputs = 0, i_cb = 1, iA = 2, iB = 3;
  {
    int a = -1, b = -1, ii = -1, ic = -1;
    for (int i = 0; i < n_in; ++i) {
      if (in_sizes[i] == M_TOK * FEAT) ii = i;
      else if (in_sizes[i] == NQ * NCODE * DIM) ic = i;
      else if (in_sizes[i] == FEAT * DIM) { if (a < 0) a = i; else b = i; }
    }
    if (ii >= 0 && ic >= 0 && a >= 0 && b >= 0) { i_inputs = ii; i_cb = ic; iA = a; iB = b; }
  }
  const float* inputs = (const float*)d_in[i_inputs];
  const float* cb     = (const float*)d_in[i_cb];
  const float* w_in   = (const float*)d_in[iA];
  const float* w_out  = (const float*)d_in[iB];

  float* out       = (float*)d_out;
  float* quantized = out;                                 // 16384*756
  float* allq      = out + (size_t)M_TOK * FEAT;          // 8*16384*256
  float* idxout    = allq + (size_t)NQ * M_TOK * DIM;     // 16384*8

  // scratch inside the quantized region (rewritten last by k_out):
  float* residual = quantized;                            // 16384*256 f32 (16.8 MB)
  float* cbn      = residual + (size_t)M_TOK * DIM;       // 8192 f32

  k_z<<<M_TOK, 256, 0, stream>>>(inputs, w_in, residual);
  k_cbnorm<<<(NQ * NCODE + 255) / 256, 256, 0, stream>>>(cb, cbn);
  for (int q = 0; q < NQ; ++q)
    k_vq<<<M_TOK / 16, 256, 0, stream>>>(cb, cbn, residual, allq, idxout, q);
  k_out<<<M_TOK, 256, 0, stream>>>(allq, w_out, quantized);
}

// Round 6
// 2899.139 us; speedup vs baseline: 1.1675x; 1.1675x over previous
//
#include <hip/hip_runtime.h>
#include <float.h>

#define M_TOK 16384   // B*T
#define DIM   256
#define NCODE 1024
#define NQ    8
#define FEAT  756
#define DELTA 1e-3f

__device__ __forceinline__ float fm(float a, float b) { return __fmul_rn(a, b); }
__device__ __forceinline__ float fa(float a, float b) { return __fadd_rn(a, b); }
__device__ __forceinline__ float fs(float a, float b) { return __fsub_rn(a, b); }

// monotone total-order key for f32 (handles negatives)
__device__ __forceinline__ unsigned fkey(float f) {
  unsigned b = __float_as_uint(f);
  return (b & 0x80000000u) ? ~b : (b | 0x80000000u);
}
__device__ __forceinline__ float funkey(unsigned k) {
  unsigned b = (k & 0x80000000u) ? (k & 0x7FFFFFFFu) : ~k;
  return __uint_as_float(b);
}

// ---- numpy pairwise_sum (SSE2-npyv) of squares, n=128 block ----
__device__ float pairwise128_sq(const float* a) {
  float V[8][4];
#pragma unroll
  for (int j = 0; j < 8; ++j)
#pragma unroll
    for (int l = 0; l < 4; ++l) { float x = a[4 * j + l]; V[j][l] = fm(x, x); }
#pragma unroll
  for (int t = 1; t < 4; ++t)
#pragma unroll
    for (int j = 0; j < 8; ++j)
#pragma unroll
      for (int l = 0; l < 4; ++l) {
        float x = a[32 * t + 4 * j + l];
        V[j][l] = fa(V[j][l], fm(x, x));
      }
  float W[4];
#pragma unroll
  for (int l = 0; l < 4; ++l) {
    float p01 = fa(V[0][l], V[1][l]), p23 = fa(V[2][l], V[3][l]);
    float p45 = fa(V[4][l], V[5][l]), p67 = fa(V[6][l], V[7][l]);
    W[l] = fa(fa(p01, p23), fa(p45, p67));
  }
  return fa(fa(W[0], W[2]), fa(W[1], W[3]));
}
__device__ float pairwise256_sq(const float* a) {
  return fa(pairwise128_sq(a), pairwise128_sq(a + 128));
}

// ---- numpy einsum contig_two f32 dot: single 4-lane acc, seq, hsum (0+2)+(1+3) ----
__device__ float dot256_np(const float* __restrict__ r, const float* __restrict__ c) {
  float L0 = 0.f, L1 = 0.f, L2 = 0.f, L3 = 0.f;
#pragma unroll 16
  for (int t = 0; t < 64; ++t) {
    float4 rv = *reinterpret_cast<const float4*>(r + 4 * t);
    float4 cv = *reinterpret_cast<const float4*>(c + 4 * t);
    L0 = fa(L0, fm(rv.x, cv.x));
    L1 = fa(L1, fm(rv.y, cv.y));
    L2 = fa(L2, fm(rv.z, cv.z));
    L3 = fa(L3, fm(rv.w, cv.w));
  }
  return fa(fa(L0, L2), fa(L1, L3));
}

#define FMA16()                                                                 \
  acc[0][0] += a.x * b.x; acc[0][1] += a.x * b.y; acc[0][2] += a.x * b.z;       \
  acc[0][3] += a.x * b.w;                                                       \
  acc[1][0] += a.y * b.x; acc[1][1] += a.y * b.y; acc[1][2] += a.y * b.z;       \
  acc[1][3] += a.y * b.w;                                                       \
  acc[2][0] += a.z * b.x; acc[2][1] += a.z * b.y; acc[2][2] += a.z * b.z;       \
  acc[2][3] += a.z * b.w;                                                       \
  acc[3][0] += a.w * b.x; acc[3][1] += a.w * b.y; acc[3][2] += a.w * b.z;       \
  acc[3][3] += a.w * b.w;

// ---- z: np-exact sequential chain per (m,d); 8 tokens/block ----
__global__ __launch_bounds__(256) void k_z8(const float* __restrict__ in,
                                            const float* __restrict__ w_in,
                                            float* __restrict__ residual) {
  const int m0 = blockIdx.x * 8;
  __shared__ float xs[8][FEAT];
  for (int i = threadIdx.x; i < 8 * FEAT; i += 256)
    xs[i / FEAT][i % FEAT] = in[(size_t)(m0 + i / FEAT) * FEAT + i % FEAT];
  __syncthreads();
  const int d = threadIdx.x;
  float acc[8] = {};
  for (int c = 0; c < 3; ++c)
    for (int f = 0; f < 252; ++f) {          // F = c*252+f ascending
      float w = w_in[(size_t)(c * 252 + f) * DIM + d];
#pragma unroll
      for (int t = 0; t < 8; ++t) acc[t] = fa(acc[t], fm(xs[t][f * 3 + c], w));
    }
#pragma unroll
  for (int t = 0; t < 8; ++t) residual[(size_t)(m0 + t) * DIM + d] = acc[t];
}

// ---- codebook row norms via numpy pairwise ----
__global__ __launch_bounds__(256) void k_cbnorm(const float* __restrict__ cb,
                                                float* __restrict__ cbn) {
  int row = blockIdx.x * 256 + threadIdx.x;
  if (row >= NQ * NCODE) return;
  cbn[row] = pairwise256_sq(&cb[(size_t)row * DIM]);
}

// ---- np token norms ----
__global__ __launch_bounds__(256) void k_t1(const float* __restrict__ residual,
                                            float* __restrict__ t1g) {
  int m = blockIdx.x * 256 + threadIdx.x;
  t1g[m] = pairwise256_sq(&residual[(size_t)m * DIM]);
}

// ---- pass A: fast f32 screen, per-token min via keyed atomicMin ----
__global__ __launch_bounds__(256) void k_screen(const float* __restrict__ cb,
                                                const float* __restrict__ cbn,
                                                const float* __restrict__ residual,
                                                unsigned* __restrict__ best_fast, int q) {
  __shared__ __align__(16) float As[16][68];
  __shared__ __align__(16) float Bs[16][68];
  const int m0 = blockIdx.x * 64;
  const int tid = threadIdx.x, ty = tid / 16, tx = tid % 16;
  const int at = tid / 4, ad0 = (tid % 4) * 4;
  const float* cbq = cb + (size_t)q * NCODE * DIM;
  const float* cbnq = cbn + q * NCODE;
  float bestv[4] = {FLT_MAX, FLT_MAX, FLT_MAX, FLT_MAX};

  for (int ct = 0; ct < 4; ++ct) {
    const int c0 = blockIdx.y * 256 + ct * 64;
    float acc[4][4] = {};
    for (int kb = 0; kb < DIM; kb += 16) {
      __syncthreads();
      {
        float4 av = *reinterpret_cast<const float4*>(&residual[(size_t)(m0 + at) * DIM + kb + ad0]);
        As[ad0 + 0][at] = av.x; As[ad0 + 1][at] = av.y;
        As[ad0 + 2][at] = av.z; As[ad0 + 3][at] = av.w;
        float4 bv = *reinterpret_cast<const float4*>(&cbq[(size_t)(c0 + at) * DIM + kb + ad0]);
        Bs[ad0 + 0][at] = bv.x; Bs[ad0 + 1][at] = bv.y;
        Bs[ad0 + 2][at] = bv.z; Bs[ad0 + 3][at] = bv.w;
      }
      __syncthreads();
#pragma unroll
      for (int dk = 0; dk < 16; ++dk) {
        float4 a = *reinterpret_cast<const float4*>(&As[dk][ty * 4]);
        float4 b = *reinterpret_cast<const float4*>(&Bs[dk][tx * 4]);
        FMA16();
      }
    }
#pragma unroll
    for (int i = 0; i < 4; ++i)
#pragma unroll
      for (int j = 0; j < 4; ++j) {
        float d = cbnq[c0 + tx * 4 + j] - 2.0f * acc[i][j];
        bestv[i] = fminf(bestv[i], d);
      }
  }
#pragma unroll
  for (int off = 8; off >= 1; off >>= 1)
#pragma unroll
    for (int i = 0; i < 4; ++i)
      bestv[i] = fminf(bestv[i], __shfl_xor(bestv[i], off, 64));
  if (tx == 0)
#pragma unroll
    for (int i = 0; i < 4; ++i)
      atomicMin(&best_fast[m0 + ty * 4 + i], fkey(bestv[i]));
}

// ---- pass B: recompute, np-exact repair of candidates within DELTA ----
__global__ __launch_bounds__(256) void k_repair(const float* __restrict__ cb,
                                                const float* __restrict__ cbn,
                                                const float* __restrict__ residual,
                                                const float* __restrict__ t1g,
                                                const unsigned* __restrict__ best_fast,
                                                unsigned long long* __restrict__ best64, int q) {
  __shared__ __align__(16) float As[16][68];
  __shared__ __align__(16) float Bs[16][68];
  const int m0 = blockIdx.x * 64;
  const int tid = threadIdx.x, ty = tid / 16, tx = tid % 16;
  const int at = tid / 4, ad0 = (tid % 4) * 4;
  const float* cbq = cb + (size_t)q * NCODE * DIM;
  const float* cbnq = cbn + q * NCODE;
  float bf[4];
#pragma unroll
  for (int i = 0; i < 4; ++i) bf[i] = funkey(best_fast[m0 + ty * 4 + i]) + DELTA;

  for (int ct = 0; ct < 4; ++ct) {
    const int c0 = blockIdx.y * 256 + ct * 64;
    float acc[4][4] = {};
    for (int kb = 0; kb < DIM; kb += 16) {
      __syncthreads();
      {
        float4 av = *reinterpret_cast<const float4*>(&residual[(size_t)(m0 + at) * DIM + kb + ad0]);
        As[ad0 + 0][at] = av.x; As[ad0 + 1][at] = av.y;
        As[ad0 + 2][at] = av.z; As[ad0 + 3][at] = av.w;
        float4 bv = *reinterpret_cast<const float4*>(&cbq[(size_t)(c0 + at) * DIM + kb + ad0]);
        Bs[ad0 + 0][at] = bv.x; Bs[ad0 + 1][at] = bv.y;
        Bs[ad0 + 2][at] = bv.z; Bs[ad0 + 3][at] = bv.w;
      }
      __syncthreads();
#pragma unroll
      for (int dk = 0; dk < 16; ++dk) {
        float4 a = *reinterpret_cast<const float4*>(&As[dk][ty * 4]);
        float4 b = *reinterpret_cast<const float4*>(&Bs[dk][tx * 4]);
        FMA16();
      }
    }
#pragma unroll
    for (int i = 0; i < 4; ++i)
#pragma unroll
      for (int j = 0; j < 4; ++j) {
        const int ci = c0 + tx * 4 + j;
        float d = cbnq[ci] - 2.0f * acc[i][j];
        if (d <= bf[i]) {
          const int m = m0 + ty * 4 + i;
          float e = dot256_np(&residual[(size_t)m * DIM], &cbq[(size_t)ci * DIM]);
          float dn = fa(fs(t1g[m], fa(e, e)), cbnq[ci]);   // np: (t1 - 2E) + t3
          unsigned long long key = ((unsigned long long)fkey(dn) << 32) | (unsigned)ci;
          atomicMin(&best64[m], key);
        }
      }
  }
}

// ---- update: residual step (np-exact f32), allq, indices ----
__global__ __launch_bounds__(256) void k_update(const float* __restrict__ cb,
                                                float* __restrict__ residual,
                                                float* __restrict__ allq,
                                                float* __restrict__ idxout,
                                                const unsigned long long* __restrict__ best64,
                                                int q) {
  const int m0 = blockIdx.x * 64;
  const int lane = threadIdx.x & 63, w = threadIdx.x >> 6;
  const float* cbq = cb + (size_t)q * NCODE * DIM;
  for (int t = w; t < 64; t += 4) {
    const size_t m = (size_t)m0 + t;
    const int ci = (int)(best64[m] & 0xFFFFFFFFull);
    const float4 cv = *reinterpret_cast<const float4*>(&cbq[(size_t)ci * DIM + lane * 4]);
    const size_t base = m * DIM + lane * 4;
    float4 r = *reinterpret_cast<const float4*>(&residual[base]);
    r.x = fs(r.x, cv.x); r.y = fs(r.y, cv.y); r.z = fs(r.z, cv.z); r.w = fs(r.w, cv.w);
    *reinterpret_cast<float4*>(&residual[base]) = r;
    *reinterpret_cast<float4*>(&allq[((size_t)q * M_TOK + m) * DIM + lane * 4]) = cv;
    if (lane == 0) idxout[m * NQ + q] = (float)ci;
  }
}

// ---- quantized = relu( (sum_q allq[q]) @ w_out ), tiled ----
__global__ __launch_bounds__(256) void k_gemm_out(const float* __restrict__ allq,
                                                  const float* __restrict__ B,
                                                  float* __restrict__ C) {
  __shared__ __align__(16) float As[16][68];
  __shared__ __align__(16) float Bs[16][68];
  const int m0 = blockIdx.x * 64, n0 = blockIdx.y * 64;
  const int tid = threadIdx.x, ty = tid / 16, tx = tid % 16;
  const int at = tid / 4, ad0 = (tid % 4) * 4;
  const int bd = tid / 16, bn = (tid % 16) * 4;
  float acc[4][4] = {};
  for (int kb = 0; kb < DIM; kb += 16) {
    __syncthreads();
    float4 av = {0.f, 0.f, 0.f, 0.f};
#pragma unroll
    for (int qq = 0; qq < NQ; ++qq) {
      float4 t = *reinterpret_cast<const float4*>(
          &allq[((size_t)qq * M_TOK + m0 + at) * DIM + kb + ad0]);
      av.x += t.x; av.y += t.y; av.z += t.z; av.w += t.w;
    }
    As[ad0 + 0][at] = av.x; As[ad0 + 1][at] = av.y;
    As[ad0 + 2][at] = av.z; As[ad0 + 3][at] = av.w;
    float4 bv = {0.f, 0.f, 0.f, 0.f};
    if (n0 + bn < FEAT)
      bv = *reinterpret_cast<const float4*>(&B[(size_t)(kb + bd) * FEAT + n0 + bn]);
    *reinterpret_cast<float4*>(&Bs[bd][bn]) = bv;
    __syncthreads();
#pragma unroll
    for (int dk = 0; dk < 16; ++dk) {
      float4 a = *reinterpret_cast<const float4*>(&As[dk][ty * 4]);
      float4 b = *reinterpret_cast<const float4*>(&Bs[dk][tx * 4]);
      FMA16();
    }
  }
  const int col = n0 + tx * 4;
  if (col < FEAT) {
#pragma unroll
    for (int i = 0; i < 4; ++i) {
      float4 o;
      o.x = fmaxf(acc[i][0], 0.f); o.y = fmaxf(acc[i][1], 0.f);
      o.z = fmaxf(acc[i][2], 0.f); o.w = fmaxf(acc[i][3], 0.f);
      *reinterpret_cast<float4*>(&C[(size_t)(m0 + ty * 4 + i) * FEAT + col]) = o;
    }
  }
}

extern "C" void kernel_launch(void* const* d_in, const int* in_sizes, int n_in,
                              void* d_out, int out_size, void* d_ws, size_t ws_size,
                              hipStream_t stream) {
  int i_inputs = 0, i_cb = 1, iA = 2, iB = 3;
  {
    int a = -1, b = -1, ii = -1, ic = -1;
    for (int i = 0; i < n_in; ++i) {
      if (in_sizes[i] == M_TOK * FEAT) ii = i;
      else if (in_sizes[i] == NQ * NCODE * DIM) ic = i;
      else if (in_sizes[i] == FEAT * DIM) { if (a < 0) a = i; else b = i; }
    }
    if (ii >= 0 && ic >= 0 && a >= 0 && b >= 0) { i_inputs = ii; i_cb = ic; iA = a; iB = b; }
  }
  const float* inputs = (const float*)d_in[i_inputs];
  const float* cb     = (const float*)d_in[i_cb];
  const float* w_in   = (const float*)d_in[iA];
  const float* w_out  = (const float*)d_in[iB];

  float* out       = (float*)d_out;
  float* quantized = out;                                 // 16384*756
  float* allq      = out + (size_t)M_TOK * FEAT;          // 8*16384*256
  float* idxout    = allq + (size_t)NQ * M_TOK * DIM;     // 16384*8

  // scratch inside the quantized region (rewritten last by k_gemm_out):
  float*    residual  = quantized;                            // 4,194,304 floats
  float*    cbn       = residual + (size_t)M_TOK * DIM;       // 8,192
  float*    t1g       = cbn + NQ * NCODE;                     // 16,384
  unsigned* best_fast = (unsigned*)(t1g + M_TOK);             // 16,384 u32
  unsigned long long* best64 =
      (unsigned long long*)(best_fast + M_TOK);               // 16,384 u64 (8B-aligned)

  k_z8<<<M_TOK / 8, 256, 0, stream>>>(inputs, w_in, residual);
  k_cbnorm<<<NQ * NCODE / 256, 256, 0, stream>>>(cb, cbn);
  for (int q = 0; q < NQ; ++q) {
    hipMemsetAsync(best_fast, 0xFF, M_TOK * sizeof(unsigned), stream);
    hipMemsetAsync(best64, 0xFF, M_TOK * sizeof(unsigned long long), stream);
    k_t1<<<M_TOK / 256, 256, 0, stream>>>(residual, t1g);
    k_screen<<<dim3(M_TOK / 64, NCODE / 256), 256, 0, stream>>>(cb, cbn, residual, best_fast, q);
    k_repair<<<dim3(M_TOK / 64, NCODE / 256), 256, 0, stream>>>(cb, cbn, residual, t1g,
                                                                best_fast, best64, q);
    k_update<<<M_TOK / 64, 256, 0, stream>>>(cb, residual, allq, idxout, best64, q);
  }
  k_gemm_out<<<dim3(M_TOK / 64, (FEAT + 63) / 64), 256, 0, stream>>>(allq, w_out, quantized);
}

// Round 7
// 2456.044 us; speedup vs baseline: 1.3781x; 1.1804x over previous
//
#include <hip/hip_runtime.h>
#include <float.h>

#define M_TOK 16384   // B*T
#define DIM   256
#define NCODE 1024
#define NQ    8
#define FEAT  756
#define DELTA 1e-3f
#define CAP   3

__device__ __forceinline__ float fm(float a, float b) { return __fmul_rn(a, b); }
__device__ __forceinline__ float fa(float a, float b) { return __fadd_rn(a, b); }
__device__ __forceinline__ float fs(float a, float b) { return __fsub_rn(a, b); }

__device__ __forceinline__ unsigned fkey(float f) {
  unsigned b = __float_as_uint(f);
  return (b & 0x80000000u) ? ~b : (b | 0x80000000u);
}

// ---- numpy pairwise_sum (SSE2-npyv) of squares, strided access ----
__device__ float pairwise128_sq_s(const float* a, int st) {
  float V[8][4];
#pragma unroll
  for (int j = 0; j < 8; ++j)
#pragma unroll
    for (int l = 0; l < 4; ++l) { float x = a[(4 * j + l) * st]; V[j][l] = fm(x, x); }
#pragma unroll
  for (int t = 1; t < 4; ++t)
#pragma unroll
    for (int j = 0; j < 8; ++j)
#pragma unroll
      for (int l = 0; l < 4; ++l) {
        float x = a[(32 * t + 4 * j + l) * st];
        V[j][l] = fa(V[j][l], fm(x, x));
      }
  float W[4];
#pragma unroll
  for (int l = 0; l < 4; ++l) {
    float p01 = fa(V[0][l], V[1][l]), p23 = fa(V[2][l], V[3][l]);
    float p45 = fa(V[4][l], V[5][l]), p67 = fa(V[6][l], V[7][l]);
    W[l] = fa(fa(p01, p23), fa(p45, p67));
  }
  return fa(fa(W[0], W[2]), fa(W[1], W[3]));
}
__device__ float pairwise256_sq_s(const float* a, int st) {
  return fa(pairwise128_sq_s(a, st), pairwise128_sq_s(a + 128 * st, st));
}

// ---- numpy einsum contig_two f32 dot; r strided (LDS), c contiguous ----
__device__ float dot256_np_s(const float* __restrict__ r, int st,
                             const float* __restrict__ c) {
  float L0 = 0.f, L1 = 0.f, L2 = 0.f, L3 = 0.f;
#pragma unroll 8
  for (int t = 0; t < 64; ++t) {
    float4 cv = *reinterpret_cast<const float4*>(c + 4 * t);
    L0 = fa(L0, fm(r[(4 * t + 0) * st], cv.x));
    L1 = fa(L1, fm(r[(4 * t + 1) * st], cv.y));
    L2 = fa(L2, fm(r[(4 * t + 2) * st], cv.z));
    L3 = fa(L3, fm(r[(4 * t + 3) * st], cv.w));
  }
  return fa(fa(L0, L2), fa(L1, L3));
}

#define FMA16()                                                                 \
  acc[0][0] += a.x * b.x; acc[0][1] += a.x * b.y; acc[0][2] += a.x * b.z;       \
  acc[0][3] += a.x * b.w;                                                       \
  acc[1][0] += a.y * b.x; acc[1][1] += a.y * b.y; acc[1][2] += a.y * b.z;       \
  acc[1][3] += a.y * b.w;                                                       \
  acc[2][0] += a.z * b.x; acc[2][1] += a.z * b.y; acc[2][2] += a.z * b.z;       \
  acc[2][3] += a.z * b.w;                                                       \
  acc[3][0] += a.w * b.x; acc[3][1] += a.w * b.y; acc[3][2] += a.w * b.z;       \
  acc[3][3] += a.w * b.w;

// ---- z: np-exact sequential chain per (m,d); 8 tokens/block ----
__global__ __launch_bounds__(256) void k_z8(const float* __restrict__ in,
                                            const float* __restrict__ w_in,
                                            float* __restrict__ residual) {
  const int m0 = blockIdx.x * 8;
  __shared__ float xs[8][FEAT];
  for (int i = threadIdx.x; i < 8 * FEAT; i += 256)
    xs[i / FEAT][i % FEAT] = in[(size_t)(m0 + i / FEAT) * FEAT + i % FEAT];
  __syncthreads();
  const int d = threadIdx.x;
  float acc[8] = {};
  for (int c = 0; c < 3; ++c)
    for (int f = 0; f < 252; ++f) {
      float w = w_in[(size_t)(c * 252 + f) * DIM + d];
#pragma unroll
      for (int t = 0; t < 8; ++t) acc[t] = fa(acc[t], fm(xs[t][f * 3 + c], w));
    }
#pragma unroll
  for (int t = 0; t < 8; ++t) residual[(size_t)(m0 + t) * DIM + d] = acc[t];
}

// ---- codebook row norms via numpy pairwise ----
__global__ __launch_bounds__(256) void k_cbnorm(const float* __restrict__ cb,
                                                float* __restrict__ cbn) {
  int row = blockIdx.x * 256 + threadIdx.x;
  if (row >= NQ * NCODE) return;
  cbn[row] = pairwise256_sq_s(&cb[(size_t)row * DIM], 1);
}

// ---- fused VQ step: screen + np-exact repair + update, one kernel per q ----
__global__ __launch_bounds__(256) void k_vq32(const float* __restrict__ cb,
                                              const float* __restrict__ cbn,
                                              float* __restrict__ residual,
                                              float* __restrict__ qsum,
                                              float* __restrict__ allq,
                                              float* __restrict__ idxout, int q) {
  __shared__ __align__(16) float rs_T[DIM][34];    // dim-major residual tile
  __shared__ __align__(16) float Bs[64][68];       // dim-major code tile (64 dims)
  __shared__ float cbn_s[NCODE];
  __shared__ float t1_s[32];
  __shared__ unsigned long long best64_s[32];
  const int m0 = blockIdx.x * 32;
  const int tid = threadIdx.x;
  const int ty = tid / 16, tx = tid % 16;          // ty: token pair, tx: code group
  const int at = tid / 4, ad0 = (tid % 4) * 4;     // staging decomposition
  const float* cbq = cb + (size_t)q * NCODE * DIM;

  // stage residual transposed
#pragma unroll
  for (int it = 0; it < 8; ++it) {
    int idx = tid + it * 256;                      // 0..2047
    int tok = idx >> 6, d4 = idx & 63;
    float4 v = *reinterpret_cast<const float4*>(&residual[(size_t)(m0 + tok) * DIM + d4 * 4]);
    rs_T[d4 * 4 + 0][tok] = v.x; rs_T[d4 * 4 + 1][tok] = v.y;
    rs_T[d4 * 4 + 2][tok] = v.z; rs_T[d4 * 4 + 3][tok] = v.w;
  }
  for (int i = tid; i < NCODE; i += 256) cbn_s[i] = cbn[q * NCODE + i];
  if (tid < 32) best64_s[tid] = 0xFFFFFFFFFFFFFFFFull;
  __syncthreads();
  if (tid < 32) t1_s[tid] = pairwise256_sq_s(&rs_T[0][tid], 34);
  __syncthreads();

  float bv[2] = {FLT_MAX, FLT_MAX}; int bi[2] = {0, 0};
  float cd[2][CAP]; int cix[2][CAP];
#pragma unroll
  for (int i = 0; i < 2; ++i)
#pragma unroll
    for (int c = 0; c < CAP; ++c) cd[i][c] = FLT_MAX;

  for (int ct = 0; ct < NCODE / 64; ++ct) {
    const int c0 = ct * 64;
    float acc[2][4] = {};
    for (int kc = 0; kc < 4; ++kc) {
      const int kb = kc * 64;
      __syncthreads();
#pragma unroll
      for (int s = 0; s < 4; ++s) {
        float4 bvv = *reinterpret_cast<const float4*>(
            &cbq[(size_t)(c0 + at) * DIM + kb + s * 16 + ad0]);
        Bs[s * 16 + ad0 + 0][at] = bvv.x; Bs[s * 16 + ad0 + 1][at] = bvv.y;
        Bs[s * 16 + ad0 + 2][at] = bvv.z; Bs[s * 16 + ad0 + 3][at] = bvv.w;
      }
      __syncthreads();
#pragma unroll 16
      for (int dk = 0; dk < 64; ++dk) {
        float2 a = *reinterpret_cast<const float2*>(&rs_T[kb + dk][ty * 2]);
        float4 b = *reinterpret_cast<const float4*>(&Bs[dk][tx * 4]);
        acc[0][0] += a.x * b.x; acc[0][1] += a.x * b.y;
        acc[0][2] += a.x * b.z; acc[0][3] += a.x * b.w;
        acc[1][0] += a.y * b.x; acc[1][1] += a.y * b.y;
        acc[1][2] += a.y * b.z; acc[1][3] += a.y * b.w;
      }
    }
#pragma unroll
    for (int i = 0; i < 2; ++i) {
      const int tokl = ty * 2 + i;
#pragma unroll
      for (int j = 0; j < 4; ++j) {
        const int code = c0 + tx * 4 + j;
        const float dfast = cbn_s[code] - 2.0f * acc[i][j];
        float pd; int pi; bool push = false;
        if (dfast < bv[i]) {
          pd = bv[i]; pi = bi[i];
          bv[i] = dfast; bi[i] = code;
          push = (pd <= dfast + DELTA);              // old best still near new
        } else if (dfast <= bv[i] + DELTA) {
          pd = dfast; pi = code; push = true;
        }
        if (push) {
          int slot = -1;
#pragma unroll
          for (int c = 0; c < CAP; ++c)
            if (slot < 0 && cd[i][c] > bv[i] + DELTA) slot = c;   // stale slot
          if (slot >= 0) { cd[i][slot] = pd; cix[i][slot] = pi; }
          else {                                     // overflow: eval now (safe)
            float e = dot256_np_s(&rs_T[0][tokl], 34, &cbq[(size_t)pi * DIM]);
            float dn = fa(fs(t1_s[tokl], fa(e, e)), cbn_s[pi]);
            atomicMin(&best64_s[tokl],
                      ((unsigned long long)fkey(dn) << 32) | (unsigned)pi);
          }
        }
      }
    }
  }

  // final fast best per token (16 tx lanes), then np-exact eval of survivors
  float fb[2] = {bv[0], bv[1]};
#pragma unroll
  for (int off = 8; off >= 1; off >>= 1)
#pragma unroll
    for (int i = 0; i < 2; ++i)
      fb[i] = fminf(fb[i], __shfl_xor(fb[i], off, 64));
#pragma unroll
  for (int i = 0; i < 2; ++i) {
    const int tokl = ty * 2 + i;
    if (bv[i] <= fb[i] + DELTA) {
      float e = dot256_np_s(&rs_T[0][tokl], 34, &cbq[(size_t)bi[i] * DIM]);
      float dn = fa(fs(t1_s[tokl], fa(e, e)), cbn_s[bi[i]]);
      atomicMin(&best64_s[tokl],
                ((unsigned long long)fkey(dn) << 32) | (unsigned)bi[i]);
    }
#pragma unroll
    for (int c = 0; c < CAP; ++c)
      if (cd[i][c] <= fb[i] + DELTA) {
        float e = dot256_np_s(&rs_T[0][tokl], 34, &cbq[(size_t)cix[i][c] * DIM]);
        float dn = fa(fs(t1_s[tokl], fa(e, e)), cbn_s[cix[i][c]]);
        atomicMin(&best64_s[tokl],
                  ((unsigned long long)fkey(dn) << 32) | (unsigned)cix[i][c]);
      }
  }
  __syncthreads();

  // update: residual step (np-exact fs), allq, qsum accumulate, index
  const int lane = tid & 63, w = tid >> 6;
  for (int t8 = 0; t8 < 8; ++t8) {
    const int tok = w * 8 + t8;
    const size_t m = (size_t)m0 + tok;
    const int ci = (int)(best64_s[tok] & 0xFFFFFFFFull);
    const float4 cv = *reinterpret_cast<const float4*>(&cbq[(size_t)ci * DIM + lane * 4]);
    float4 r;
    r.x = fs(rs_T[lane * 4 + 0][tok], cv.x);
    r.y = fs(rs_T[lane * 4 + 1][tok], cv.y);
    r.z = fs(rs_T[lane * 4 + 2][tok], cv.z);
    r.w = fs(rs_T[lane * 4 + 3][tok], cv.w);
    const size_t base = m * DIM + lane * 4;
    *reinterpret_cast<float4*>(&residual[base]) = r;
    *reinterpret_cast<float4*>(&allq[((size_t)q * M_TOK + m) * DIM + lane * 4]) = cv;
    if (q == 0) {
      *reinterpret_cast<float4*>(&qsum[base]) = cv;
    } else {
      float4 s4 = *reinterpret_cast<const float4*>(&qsum[base]);
      s4.x += cv.x; s4.y += cv.y; s4.z += cv.z; s4.w += cv.w;
      *reinterpret_cast<float4*>(&qsum[base]) = s4;
    }
    if (lane == 0) idxout[m * NQ + q] = (float)ci;
  }
}

// ---- quantized = relu( qsum @ w_out ), tiled 64x64 ----
__global__ __launch_bounds__(256) void k_gemm_out(const float* __restrict__ A,
                                                  const float* __restrict__ B,
                                                  float* __restrict__ C) {
  __shared__ __align__(16) float As[16][68];
  __shared__ __align__(16) float Bs[16][68];
  const int m0 = blockIdx.x * 64, n0 = blockIdx.y * 64;
  const int tid = threadIdx.x, ty = tid / 16, tx = tid % 16;
  const int at = tid / 4, ad0 = (tid % 4) * 4;
  const int bd = tid / 16, bn = (tid % 16) * 4;
  float acc[4][4] = {};
  for (int kb = 0; kb < DIM; kb += 16) {
    __syncthreads();
    float4 av = *reinterpret_cast<const float4*>(&A[(size_t)(m0 + at) * DIM + kb + ad0]);
    As[ad0 + 0][at] = av.x; As[ad0 + 1][at] = av.y;
    As[ad0 + 2][at] = av.z; As[ad0 + 3][at] = av.w;
    float4 bv = {0.f, 0.f, 0.f, 0.f};
    if (n0 + bn < FEAT)
      bv = *reinterpret_cast<const float4*>(&B[(size_t)(kb + bd) * FEAT + n0 + bn]);
    *reinterpret_cast<float4*>(&Bs[bd][bn]) = bv;
    __syncthreads();
#pragma unroll
    for (int dk = 0; dk < 16; ++dk) {
      float4 a = *reinterpret_cast<const float4*>(&As[dk][ty * 4]);
      float4 b = *reinterpret_cast<const float4*>(&Bs[dk][tx * 4]);
      FMA16();
    }
  }
  const int col = n0 + tx * 4;
  if (col < FEAT) {
#pragma unroll
    for (int i = 0; i < 4; ++i) {
      float4 o;
      o.x = fmaxf(acc[i][0], 0.f); o.y = fmaxf(acc[i][1], 0.f);
      o.z = fmaxf(acc[i][2], 0.f); o.w = fmaxf(acc[i][3], 0.f);
      *reinterpret_cast<float4*>(&C[(size_t)(m0 + ty * 4 + i) * FEAT + col]) = o;
    }
  }
}

extern "C" void kernel_launch(void* const* d_in, const int* in_sizes, int n_in,
                              void* d_out, int out_size, void* d_ws, size_t ws_size,
                              hipStream_t stream) {
  int i_inputs = 0, i_cb = 1, iA = 2, iB = 3;
  {
    int a = -1, b = -1, ii = -1, ic = -1;
    for (int i = 0; i < n_in; ++i) {
      if (in_sizes[i] == M_TOK * FEAT) ii = i;
      else if (in_sizes[i] == NQ * NCODE * DIM) ic = i;
      else if (in_sizes[i] == FEAT * DIM) { if (a < 0) a = i; else b = i; }
    }
    if (ii >= 0 && ic >= 0 && a >= 0 && b >= 0) { i_inputs = ii; i_cb = ic; iA = a; iB = b; }
  }
  const float* inputs = (const float*)d_in[i_inputs];
  const float* cb     = (const float*)d_in[i_cb];
  const float* w_in   = (const float*)d_in[iA];
  const float* w_out  = (const float*)d_in[iB];

  float* out       = (float*)d_out;
  float* quantized = out;                                 // 16384*756
  float* allq      = out + (size_t)M_TOK * FEAT;          // 8*16384*256
  float* idxout    = allq + (size_t)NQ * M_TOK * DIM;     // 16384*8

  // scratch inside the quantized region (rewritten last by k_gemm_out):
  float* residual = quantized;                            // 4,194,304 floats
  float* qsum     = residual + (size_t)M_TOK * DIM;       // 4,194,304 floats
  float* cbn      = qsum + (size_t)M_TOK * DIM;           // 8,192 floats  (33.6MB<47MB)

  k_z8<<<M_TOK / 8, 256, 0, stream>>>(inputs, w_in, residual);
  k_cbnorm<<<NQ * NCODE / 256, 256, 0, stream>>>(cb, cbn);
  for (int q = 0; q < NQ; ++q)
    k_vq32<<<M_TOK / 32, 256, 0, stream>>>(cb, cbn, residual, qsum, allq, idxout, q);
  k_gemm_out<<<dim3(M_TOK / 64, (FEAT + 63) / 64), 256, 0, stream>>>(qsum, w_out, quantized);
}

// Round 8
// 1802.294 us; speedup vs baseline: 1.8780x; 1.3627x over previous
//
#include <hip/hip_runtime.h>
#include <float.h>

#define M_TOK 16384   // B*T
#define DIM   256
#define NCODE 1024
#define NQ    8
#define FEAT  756
#define DELTA 0.15f

using short8 = __attribute__((ext_vector_type(8))) short;  // 8 bf16
using f32x4  = __attribute__((ext_vector_type(4))) float;

__device__ __forceinline__ float fm(float a, float b) { return __fmul_rn(a, b); }
__device__ __forceinline__ float fa(float a, float b) { return __fadd_rn(a, b); }
__device__ __forceinline__ float fs(float a, float b) { return __fsub_rn(a, b); }

__device__ __forceinline__ unsigned fkey(float f) {
  unsigned b = __float_as_uint(f);
  return (b & 0x80000000u) ? ~b : (b | 0x80000000u);
}
__device__ __forceinline__ unsigned short bf16rne(float x) {
  unsigned b = __float_as_uint(x);
  return (unsigned short)((b + 0x7FFFu + ((b >> 16) & 1u)) >> 16);
}

// ---- numpy pairwise_sum (SSE2-npyv) of squares ----
__device__ float pairwise128_sq(const float* a) {
  float V[8][4];
#pragma unroll
  for (int j = 0; j < 8; ++j)
#pragma unroll
    for (int l = 0; l < 4; ++l) { float x = a[4 * j + l]; V[j][l] = fm(x, x); }
#pragma unroll
  for (int t = 1; t < 4; ++t)
#pragma unroll
    for (int j = 0; j < 8; ++j)
#pragma unroll
      for (int l = 0; l < 4; ++l) {
        float x = a[32 * t + 4 * j + l];
        V[j][l] = fa(V[j][l], fm(x, x));
      }
  float W[4];
#pragma unroll
  for (int l = 0; l < 4; ++l) {
    float p01 = fa(V[0][l], V[1][l]), p23 = fa(V[2][l], V[3][l]);
    float p45 = fa(V[4][l], V[5][l]), p67 = fa(V[6][l], V[7][l]);
    W[l] = fa(fa(p01, p23), fa(p45, p67));
  }
  return fa(fa(W[0], W[2]), fa(W[1], W[3]));
}
__device__ float pairwise256_sq(const float* a) {
  return fa(pairwise128_sq(a), pairwise128_sq(a + 128));
}

// ---- numpy einsum contig_two f32 dot ----
__device__ float dot256_np(const float* __restrict__ r, const float* __restrict__ c) {
  float L0 = 0.f, L1 = 0.f, L2 = 0.f, L3 = 0.f;
#pragma unroll 8
  for (int t = 0; t < 64; ++t) {
    float4 rv = *reinterpret_cast<const float4*>(r + 4 * t);
    float4 cv = *reinterpret_cast<const float4*>(c + 4 * t);
    L0 = fa(L0, fm(rv.x, cv.x));
    L1 = fa(L1, fm(rv.y, cv.y));
    L2 = fa(L2, fm(rv.z, cv.z));
    L3 = fa(L3, fm(rv.w, cv.w));
  }
  return fa(fa(L0, L2), fa(L1, L3));
}

__device__ __forceinline__ void np_eval(const float* __restrict__ rrow,
                                        const float* __restrict__ crow,
                                        float t1, float t3, int code,
                                        unsigned long long* __restrict__ dst) {
  float e = dot256_np(rrow, crow);
  float dn = fa(fs(t1, fa(e, e)), t3);
  atomicMin(dst, ((unsigned long long)fkey(dn) << 32) | (unsigned)code);
}

#define FMA16()                                                                 \
  acc[0][0] += a.x * b.x; acc[0][1] += a.x * b.y; acc[0][2] += a.x * b.z;       \
  acc[0][3] += a.x * b.w;                                                       \
  acc[1][0] += a.y * b.x; acc[1][1] += a.y * b.y; acc[1][2] += a.y * b.z;       \
  acc[1][3] += a.y * b.w;                                                       \
  acc[2][0] += a.z * b.x; acc[2][1] += a.z * b.y; acc[2][2] += a.z * b.z;       \
  acc[2][3] += a.z * b.w;                                                       \
  acc[3][0] += a.w * b.x; acc[3][1] += a.w * b.y; acc[3][2] += a.w * b.z;       \
  acc[3][3] += a.w * b.w;

// ---- z: np-exact sequential chain per (m,d); 8 tokens/block ----
__global__ __launch_bounds__(256) void k_z8(const float* __restrict__ in,
                                            const float* __restrict__ w_in,
                                            float* __restrict__ residual) {
  const int m0 = blockIdx.x * 8;
  __shared__ float xs[8][FEAT];
  for (int i = threadIdx.x; i < 8 * FEAT; i += 256)
    xs[i / FEAT][i % FEAT] = in[(size_t)(m0 + i / FEAT) * FEAT + i % FEAT];
  __syncthreads();
  const int d = threadIdx.x;
  float acc[8] = {};
  for (int c = 0; c < 3; ++c)
    for (int f = 0; f < 252; ++f) {
      float w = w_in[(size_t)(c * 252 + f) * DIM + d];
#pragma unroll
      for (int t = 0; t < 8; ++t) acc[t] = fa(acc[t], fm(xs[t][f * 3 + c], w));
    }
#pragma unroll
  for (int t = 0; t < 8; ++t) residual[(size_t)(m0 + t) * DIM + d] = acc[t];
}

// ---- codebook row norms (np pairwise) ----
__global__ __launch_bounds__(256) void k_cbnorm(const float* __restrict__ cb,
                                                float* __restrict__ cbn) {
  int row = blockIdx.x * 256 + threadIdx.x;
  if (row >= NQ * NCODE) return;
  cbn[row] = pairwise256_sq(&cb[(size_t)row * DIM]);
}

// ---- codebook f32 -> bf16 bits ----
__global__ __launch_bounds__(256) void k_cb16(const float* __restrict__ cb,
                                              unsigned short* __restrict__ cb16) {
  size_t i = (size_t)blockIdx.x * 1024 + (size_t)threadIdx.x * 4;
  float4 v = *reinterpret_cast<const float4*>(&cb[i]);
  ushort4 o;
  o.x = bf16rne(v.x); o.y = bf16rne(v.y); o.z = bf16rne(v.z); o.w = bf16rne(v.w);
  *reinterpret_cast<ushort4*>(&cb16[i]) = o;
}

// ---- np token norms + best64 reset ----
__global__ __launch_bounds__(256) void k_t1init(const float* __restrict__ residual,
                                                float* __restrict__ t1g,
                                                unsigned long long* __restrict__ best64) {
  int m = blockIdx.x * 256 + threadIdx.x;
  t1g[m] = pairwise256_sq(&residual[(size_t)m * DIM]);
  best64[m] = 0xFFFFFFFFFFFFFFFFull;
}

// ---- MFMA bf16 screen + np-exact repair of near-ties ----
__global__ __launch_bounds__(256) void k_screen(
    const unsigned short* __restrict__ cb16, const float* __restrict__ cb,
    const float* __restrict__ cbn, const float* __restrict__ residual,
    const float* __restrict__ t1g, unsigned long long* __restrict__ best64, int q) {
  __shared__ __align__(16) unsigned short Bs[64][264];   // +8 pad: kills 16-way conflict
  __shared__ float cbn_s[256];
  const int m0 = blockIdx.x * 64;
  const int cbase = blockIdx.y * 256;
  const int tid = threadIdx.x, w = tid >> 6, lane = tid & 63;
  const int lrow = lane & 15, lk = lane >> 4;
  const unsigned short* cbq16 = cb16 + (size_t)q * NCODE * DIM;
  const float* cbqf = cb + (size_t)q * NCODE * DIM;

  cbn_s[tid] = cbn[q * NCODE + cbase + tid];

  // A fragments in registers: token = m0 + w*16 + lrow, k = s*32 + lk*8 + j
  const int mtokA = m0 + w * 16 + lrow;
  short8 afr[8];
  {
    const float* rrow = &residual[(size_t)mtokA * DIM];
#pragma unroll
    for (int s = 0; s < 8; ++s) {
      float4 x0 = *reinterpret_cast<const float4*>(&rrow[s * 32 + lk * 8]);
      float4 x1 = *reinterpret_cast<const float4*>(&rrow[s * 32 + lk * 8 + 4]);
      short8 t;
      t[0] = (short)bf16rne(x0.x); t[1] = (short)bf16rne(x0.y);
      t[2] = (short)bf16rne(x0.z); t[3] = (short)bf16rne(x0.w);
      t[4] = (short)bf16rne(x1.x); t[5] = (short)bf16rne(x1.y);
      t[6] = (short)bf16rne(x1.z); t[7] = (short)bf16rne(x1.w);
      afr[s] = t;
    }
  }

  float bv[4] = {FLT_MAX, FLT_MAX, FLT_MAX, FLT_MAX};
  int bi[4] = {0, 0, 0, 0};
  float cd[4][2]; int cix[4][2];
#pragma unroll
  for (int r = 0; r < 4; ++r) { cd[r][0] = FLT_MAX; cd[r][1] = FLT_MAX; cix[r][0] = 0; cix[r][1] = 0; }

  for (int ct = 0; ct < 4; ++ct) {
    __syncthreads();
    {  // stage B tile: 64 codes x 256 dims bf16
      int r = tid >> 2, seg = tid & 3;
      const uint4* src = reinterpret_cast<const uint4*>(
          &cbq16[(size_t)(cbase + ct * 64 + r) * DIM + seg * 64]);
      uint4* dst = reinterpret_cast<uint4*>(&Bs[r][seg * 64]);
#pragma unroll
      for (int u = 0; u < 8; ++u) dst[u] = src[u];
    }
    __syncthreads();

    f32x4 acc[4];
#pragma unroll
    for (int f = 0; f < 4; ++f) acc[f] = (f32x4){0.f, 0.f, 0.f, 0.f};
#pragma unroll
    for (int s = 0; s < 8; ++s) {
#pragma unroll
      for (int f = 0; f < 4; ++f) {
        short8 bfr = *reinterpret_cast<const short8*>(&Bs[f * 16 + lrow][s * 32 + lk * 8]);
        acc[f] = __builtin_amdgcn_mfma_f32_16x16x32_bf16(afr[s], bfr, acc[f], 0, 0, 0);
      }
    }

#pragma unroll
    for (int f = 0; f < 4; ++f) {
      const int codeL = ct * 64 + f * 16 + lrow;
      const int code = cbase + codeL;
      const float t3 = cbn_s[codeL];
#pragma unroll
      for (int r = 0; r < 4; ++r) {
        const float dfast = t3 - 2.0f * acc[f][r];
        float pd; int pi; bool push = false;
        if (dfast < bv[r]) {
          pd = bv[r]; pi = bi[r];
          bv[r] = dfast; bi[r] = code;
          push = (pd <= dfast + DELTA);
        } else if (dfast <= bv[r] + DELTA) {
          pd = dfast; pi = code; push = true;
        }
        if (push) {
          if (cd[r][0] > bv[r] + DELTA) { cd[r][0] = pd; cix[r][0] = pi; }
          else if (cd[r][1] > bv[r] + DELTA) { cd[r][1] = pd; cix[r][1] = pi; }
          else {  // overflow: evaluate immediately (always safe)
            const int m = m0 + w * 16 + lk * 4 + r;
            np_eval(&residual[(size_t)m * DIM], &cbqf[(size_t)pi * DIM],
                    t1g[m], cbn_s[pi - cbase], pi, &best64[m]);
          }
        }
      }
    }
  }

  // block-local best across the 16 col-lanes of each row group
  float fb[4] = {bv[0], bv[1], bv[2], bv[3]};
#pragma unroll
  for (int off = 8; off >= 1; off >>= 1)
#pragma unroll
    for (int r = 0; r < 4; ++r)
      fb[r] = fminf(fb[r], __shfl_xor(fb[r], off, 64));

#pragma unroll
  for (int r = 0; r < 4; ++r) {
    const int m = m0 + w * 16 + lk * 4 + r;
    const float* rrow = &residual[(size_t)m * DIM];
    const float t1 = t1g[m];
    if (bv[r] <= fb[r] + DELTA)
      np_eval(rrow, &cbqf[(size_t)bi[r] * DIM], t1, cbn_s[bi[r] - cbase], bi[r], &best64[m]);
    if (cd[r][0] <= fb[r] + DELTA)
      np_eval(rrow, &cbqf[(size_t)cix[r][0] * DIM], t1, cbn_s[cix[r][0] - cbase], cix[r][0], &best64[m]);
    if (cd[r][1] <= fb[r] + DELTA)
      np_eval(rrow, &cbqf[(size_t)cix[r][1] * DIM], t1, cbn_s[cix[r][1] - cbase], cix[r][1], &best64[m]);
  }
}

// ---- update: residual step (np fs), allq, qsum, idx ----
__global__ __launch_bounds__(256) void k_upd(const float* __restrict__ cb,
                                             float* __restrict__ residual,
                                             float* __restrict__ qsum,
                                             float* __restrict__ allq,
                                             float* __restrict__ idxout,
                                             const unsigned long long* __restrict__ best64,
                                             int q) {
  const int m0 = blockIdx.x * 64;
  const int lane = threadIdx.x & 63, w = threadIdx.x >> 6;
  const float* cbq = cb + (size_t)q * NCODE * DIM;
  for (int t = 0; t < 16; ++t) {
    const size_t m = (size_t)m0 + w * 16 + t;
    const int ci = (int)(best64[m] & 0xFFFFFFFFull);
    const float4 cv = *reinterpret_cast<const float4*>(&cbq[(size_t)ci * DIM + lane * 4]);
    const size_t base = m * DIM + lane * 4;
    float4 r = *reinterpret_cast<const float4*>(&residual[base]);
    r.x = fs(r.x, cv.x); r.y = fs(r.y, cv.y); r.z = fs(r.z, cv.z); r.w = fs(r.w, cv.w);
    *reinterpret_cast<float4*>(&residual[base]) = r;
    *reinterpret_cast<float4*>(&allq[((size_t)q * M_TOK + m) * DIM + lane * 4]) = cv;
    if (q == 0) {
      *reinterpret_cast<float4*>(&qsum[base]) = cv;
    } else {
      float4 s4 = *reinterpret_cast<const float4*>(&qsum[base]);
      s4.x += cv.x; s4.y += cv.y; s4.z += cv.z; s4.w += cv.w;
      *reinterpret_cast<float4*>(&qsum[base]) = s4;
    }
    if (lane == 0) idxout[m * NQ + q] = (float)ci;
  }
}

// ---- quantized = relu( qsum @ w_out ), tiled 64x64 ----
__global__ __launch_bounds__(256) void k_gemm_out(const float* __restrict__ A,
                                                  const float* __restrict__ B,
                                                  float* __restrict__ C) {
  __shared__ __align__(16) float As[16][68];
  __shared__ __align__(16) float Bs[16][68];
  const int m0 = blockIdx.x * 64, n0 = blockIdx.y * 64;
  const int tid = threadIdx.x, ty = tid / 16, tx = tid % 16;
  const int at = tid / 4, ad0 = (tid % 4) * 4;
  const int bd = tid / 16, bn = (tid % 16) * 4;
  float acc[4][4] = {};
  for (int kb = 0; kb < DIM; kb += 16) {
    __syncthreads();
    float4 av = *reinterpret_cast<const float4*>(&A[(size_t)(m0 + at) * DIM + kb + ad0]);
    As[ad0 + 0][at] = av.x; As[ad0 + 1][at] = av.y;
    As[ad0 + 2][at] = av.z; As[ad0 + 3][at] = av.w;
    float4 bv = {0.f, 0.f, 0.f, 0.f};
    if (n0 + bn < FEAT)
      bv = *reinterpret_cast<const float4*>(&B[(size_t)(kb + bd) * FEAT + n0 + bn]);
    *reinterpret_cast<float4*>(&Bs[bd][bn]) = bv;
    __syncthreads();
#pragma unroll
    for (int dk = 0; dk < 16; ++dk) {
      float4 a = *reinterpret_cast<const float4*>(&As[dk][ty * 4]);
      float4 b = *reinterpret_cast<const float4*>(&Bs[dk][tx * 4]);
      FMA16();
    }
  }
  const int col = n0 + tx * 4;
  if (col < FEAT) {
#pragma unroll
    for (int i = 0; i < 4; ++i) {
      float4 o;
      o.x = fmaxf(acc[i][0], 0.f); o.y = fmaxf(acc[i][1], 0.f);
      o.z = fmaxf(acc[i][2], 0.f); o.w = fmaxf(acc[i][3], 0.f);
      *reinterpret_cast<float4*>(&C[(size_t)(m0 + ty * 4 + i) * FEAT + col]) = o;
    }
  }
}

extern "C" void kernel_launch(void* const* d_in, const int* in_sizes, int n_in,
                              void* d_out, int out_size, void* d_ws, size_t ws_size,
                              hipStream_t stream) {
  int i_inputs = 0, i_cb = 1, iA = 2, iB = 3;
  {
    int a = -1, b = -1, ii = -1, ic = -1;
    for (int i = 0; i < n_in; ++i) {
      if (in_sizes[i] == M_TOK * FEAT) ii = i;
      else if (in_sizes[i] == NQ * NCODE * DIM) ic = i;
      else if (in_sizes[i] == FEAT * DIM) { if (a < 0) a = i; else b = i; }
    }
    if (ii >= 0 && ic >= 0 && a >= 0 && b >= 0) { i_inputs = ii; i_cb = ic; iA = a; iB = b; }
  }
  const float* inputs = (const float*)d_in[i_inputs];
  const float* cb     = (const float*)d_in[i_cb];
  const float* w_in   = (const float*)d_in[iA];
  const float* w_out  = (const float*)d_in[iB];

  float* out       = (float*)d_out;
  float* quantized = out;                                 // 16384*756
  float* allq      = out + (size_t)M_TOK * FEAT;          // 8*16384*256
  float* idxout    = allq + (size_t)NQ * M_TOK * DIM;     // 16384*8

  // scratch inside the quantized region (rewritten last by k_gemm_out):
  float* residual = quantized;                            // 4,194,304 f
  float* qsum     = residual + (size_t)M_TOK * DIM;       // 4,194,304 f
  float* cbn      = qsum + (size_t)M_TOK * DIM;           // 8,192 f
  float* t1g      = cbn + NQ * NCODE;                     // 16,384 f
  unsigned long long* best64 = (unsigned long long*)(t1g + M_TOK);   // 16,384 u64
  unsigned short* cb16 = (unsigned short*)(best64 + M_TOK);          // 2M bf16 (4MB)
  // total 9,494,528 floats < 12,386,304 available

  k_z8<<<M_TOK / 8, 256, 0, stream>>>(inputs, w_in, residual);
  k_cbnorm<<<NQ * NCODE / 256, 256, 0, stream>>>(cb, cbn);
  k_cb16<<<NQ * NCODE * DIM / 1024, 256, 0, stream>>>(cb, cb16);
  k_t1init<<<M_TOK / 256, 256, 0, stream>>>(residual, t1g, best64);
  for (int q = 0; q < NQ; ++q) {
    k_screen<<<dim3(M_TOK / 64, NCODE / 256), 256, 0, stream>>>(cb16, cb, cbn, residual,
                                                                t1g, best64, q);
    k_upd<<<M_TOK / 64, 256, 0, stream>>>(cb, residual, qsum, allq, idxout, best64, q);
    if (q < NQ - 1)
      k_t1init<<<M_TOK / 256, 256, 0, stream>>>(residual, t1g, best64);
  }
  k_gemm_out<<<dim3(M_TOK / 64, (FEAT + 63) / 64), 256, 0, stream>>>(qsum, w_out, quantized);
}

// Round 9
// 1496.839 us; speedup vs baseline: 2.2613x; 1.2041x over previous
//
#include <hip/hip_runtime.h>
#include <float.h>

#define M_TOK 16384   // B*T
#define DIM   256
#define NCODE 1024
#define NQ    8
#define FEAT  756
#define DELTA 0.06f

using short8 = __attribute__((ext_vector_type(8))) short;  // 8 bf16
using f32x4  = __attribute__((ext_vector_type(4))) float;

__device__ __forceinline__ float fm(float a, float b) { return __fmul_rn(a, b); }
__device__ __forceinline__ float fa(float a, float b) { return __fadd_rn(a, b); }
__device__ __forceinline__ float fs(float a, float b) { return __fsub_rn(a, b); }

__device__ __forceinline__ unsigned fkey(float f) {
  unsigned b = __float_as_uint(f);
  return (b & 0x80000000u) ? ~b : (b | 0x80000000u);
}
__device__ __forceinline__ unsigned short bf16rne(float x) {
  unsigned b = __float_as_uint(x);
  return (unsigned short)((b + 0x7FFFu + ((b >> 16) & 1u)) >> 16);
}

// ---- numpy pairwise_sum (SSE2-npyv) of squares ----
__device__ float pairwise128_sq(const float* a) {
  float V[8][4];
#pragma unroll
  for (int j = 0; j < 8; ++j)
#pragma unroll
    for (int l = 0; l < 4; ++l) { float x = a[4 * j + l]; V[j][l] = fm(x, x); }
#pragma unroll
  for (int t = 1; t < 4; ++t)
#pragma unroll
    for (int j = 0; j < 8; ++j)
#pragma unroll
      for (int l = 0; l < 4; ++l) {
        float x = a[32 * t + 4 * j + l];
        V[j][l] = fa(V[j][l], fm(x, x));
      }
  float W[4];
#pragma unroll
  for (int l = 0; l < 4; ++l) {
    float p01 = fa(V[0][l], V[1][l]), p23 = fa(V[2][l], V[3][l]);
    float p45 = fa(V[4][l], V[5][l]), p67 = fa(V[6][l], V[7][l]);
    W[l] = fa(fa(p01, p23), fa(p45, p67));
  }
  return fa(fa(W[0], W[2]), fa(W[1], W[3]));
}
__device__ float pairwise256_sq(const float* a) {
  return fa(pairwise128_sq(a), pairwise128_sq(a + 128));
}

// ---- numpy einsum contig_two f32 dot ----
__device__ float dot256_np(const float* __restrict__ r, const float* __restrict__ c) {
  float L0 = 0.f, L1 = 0.f, L2 = 0.f, L3 = 0.f;
#pragma unroll 8
  for (int t = 0; t < 64; ++t) {
    float4 rv = *reinterpret_cast<const float4*>(r + 4 * t);
    float4 cv = *reinterpret_cast<const float4*>(c + 4 * t);
    L0 = fa(L0, fm(rv.x, cv.x));
    L1 = fa(L1, fm(rv.y, cv.y));
    L2 = fa(L2, fm(rv.z, cv.z));
    L3 = fa(L3, fm(rv.w, cv.w));
  }
  return fa(fa(L0, L2), fa(L1, L3));
}

__device__ __forceinline__ void np_eval(const float* __restrict__ rrow,
                                        const float* __restrict__ crow,
                                        float t1, float t3, int code,
                                        unsigned long long* __restrict__ dst) {
  float e = dot256_np(rrow, crow);
  float dn = fa(fs(t1, fa(e, e)), t3);
  atomicMin(dst, ((unsigned long long)fkey(dn) << 32) | (unsigned)code);
}

#define FMA16()                                                                 \
  acc[0][0] += a.x * b.x; acc[0][1] += a.x * b.y; acc[0][2] += a.x * b.z;       \
  acc[0][3] += a.x * b.w;                                                       \
  acc[1][0] += a.y * b.x; acc[1][1] += a.y * b.y; acc[1][2] += a.y * b.z;       \
  acc[1][3] += a.y * b.w;                                                       \
  acc[2][0] += a.z * b.x; acc[2][1] += a.z * b.y; acc[2][2] += a.z * b.z;       \
  acc[2][3] += a.z * b.w;                                                       \
  acc[3][0] += a.w * b.x; acc[3][1] += a.w * b.y; acc[3][2] += a.w * b.z;       \
  acc[3][3] += a.w * b.w;

// ---- z: np-exact sequential chain per (m,d); 16 tokens/block ----
__global__ __launch_bounds__(256) void k_z16(const float* __restrict__ in,
                                             const float* __restrict__ w_in,
                                             float* __restrict__ residual) {
  const int m0 = blockIdx.x * 16;
  __shared__ float xs[16][FEAT];
  for (int i = threadIdx.x; i < 16 * FEAT; i += 256)
    xs[i / FEAT][i % FEAT] = in[(size_t)m0 * FEAT + i];
  __syncthreads();
  const int d = threadIdx.x;
  float acc[16] = {};
  for (int c = 0; c < 3; ++c)
    for (int f = 0; f < 252; ++f) {
      float w = w_in[(size_t)(c * 252 + f) * DIM + d];
#pragma unroll
      for (int t = 0; t < 16; ++t) acc[t] = fa(acc[t], fm(xs[t][f * 3 + c], w));
    }
#pragma unroll
  for (int t = 0; t < 16; ++t) residual[(size_t)(m0 + t) * DIM + d] = acc[t];
}

// ---- codebook row norms (np pairwise) ----
__global__ __launch_bounds__(256) void k_cbnorm(const float* __restrict__ cb,
                                                float* __restrict__ cbn) {
  int row = blockIdx.x * 256 + threadIdx.x;
  if (row >= NQ * NCODE) return;
  cbn[row] = pairwise256_sq(&cb[(size_t)row * DIM]);
}

// ---- codebook f32 -> bf16 bits ----
__global__ __launch_bounds__(256) void k_cb16(const float* __restrict__ cb,
                                              unsigned short* __restrict__ cb16) {
  size_t i = (size_t)blockIdx.x * 1024 + (size_t)threadIdx.x * 4;
  float4 v = *reinterpret_cast<const float4*>(&cb[i]);
  ushort4 o;
  o.x = bf16rne(v.x); o.y = bf16rne(v.y); o.z = bf16rne(v.z); o.w = bf16rne(v.w);
  *reinterpret_cast<ushort4*>(&cb16[i]) = o;
}

// ---- np token norms + best64 reset ----
__global__ __launch_bounds__(256) void k_t1init(const float* __restrict__ residual,
                                                float* __restrict__ t1g,
                                                unsigned long long* __restrict__ best64) {
  int m = blockIdx.x * 256 + threadIdx.x;
  t1g[m] = pairwise256_sq(&residual[(size_t)m * DIM]);
  best64[m] = 0xFFFFFFFFFFFFFFFFull;
}

// ---- MFMA bf16 screen + np-exact repair of near-ties ----
__global__ __launch_bounds__(256) void k_screen(
    const unsigned short* __restrict__ cb16, const float* __restrict__ cb,
    const float* __restrict__ cbn, const float* __restrict__ residual,
    const float* __restrict__ t1g, unsigned long long* __restrict__ best64, int q) {
  __shared__ __align__(16) unsigned short Bs[64][264];   // +8 pad: kills 16-way conflict
  __shared__ float cbn_s[256];
  const int m0 = blockIdx.x * 64;
  const int cbase = blockIdx.y * 256;
  const int tid = threadIdx.x, w = tid >> 6, lane = tid & 63;
  const int lrow = lane & 15, lk = lane >> 4;
  const unsigned short* cbq16 = cb16 + (size_t)q * NCODE * DIM;
  const float* cbqf = cb + (size_t)q * NCODE * DIM;

  cbn_s[tid] = cbn[q * NCODE + cbase + tid];

  // A fragments in registers: token = m0 + w*16 + lrow, k = s*32 + lk*8 + j
  const int mtokA = m0 + w * 16 + lrow;
  short8 afr[8];
  {
    const float* rrow = &residual[(size_t)mtokA * DIM];
#pragma unroll
    for (int s = 0; s < 8; ++s) {
      float4 x0 = *reinterpret_cast<const float4*>(&rrow[s * 32 + lk * 8]);
      float4 x1 = *reinterpret_cast<const float4*>(&rrow[s * 32 + lk * 8 + 4]);
      short8 t;
      t[0] = (short)bf16rne(x0.x); t[1] = (short)bf16rne(x0.y);
      t[2] = (short)bf16rne(x0.z); t[3] = (short)bf16rne(x0.w);
      t[4] = (short)bf16rne(x1.x); t[5] = (short)bf16rne(x1.y);
      t[6] = (short)bf16rne(x1.z); t[7] = (short)bf16rne(x1.w);
      afr[s] = t;
    }
  }

  float bv[4] = {FLT_MAX, FLT_MAX, FLT_MAX, FLT_MAX};
  int bi[4] = {0, 0, 0, 0};
  float cd[4][2]; int cix[4][2];
#pragma unroll
  for (int r = 0; r < 4; ++r) { cd[r][0] = FLT_MAX; cd[r][1] = FLT_MAX; cix[r][0] = 0; cix[r][1] = 0; }

  for (int ct = 0; ct < 4; ++ct) {
    __syncthreads();
    {  // stage B tile: 64 codes x 256 dims bf16
      int r = tid >> 2, seg = tid & 3;
      const uint4* src = reinterpret_cast<const uint4*>(
          &cbq16[(size_t)(cbase + ct * 64 + r) * DIM + seg * 64]);
      uint4* dst = reinterpret_cast<uint4*>(&Bs[r][seg * 64]);
#pragma unroll
      for (int u = 0; u < 8; ++u) dst[u] = src[u];
    }
    __syncthreads();

    f32x4 acc[4];
#pragma unroll
    for (int f = 0; f < 4; ++f) acc[f] = (f32x4){0.f, 0.f, 0.f, 0.f};
#pragma unroll
    for (int s = 0; s < 8; ++s) {
#pragma unroll
      for (int f = 0; f < 4; ++f) {
        short8 bfr = *reinterpret_cast<const short8*>(&Bs[f * 16 + lrow][s * 32 + lk * 8]);
        acc[f] = __builtin_amdgcn_mfma_f32_16x16x32_bf16(afr[s], bfr, acc[f], 0, 0, 0);
      }
    }

#pragma unroll
    for (int f = 0; f < 4; ++f) {
      const int codeL = ct * 64 + f * 16 + lrow;
      const int code = cbase + codeL;
      const float t3 = cbn_s[codeL];
#pragma unroll
      for (int r = 0; r < 4; ++r) {
        const float dfast = t3 - 2.0f * acc[f][r];
        float pd; int pi; bool push = false;
        if (dfast < bv[r]) {
          pd = bv[r]; pi = bi[r];
          bv[r] = dfast; bi[r] = code;
          push = (pd <= dfast + DELTA);
        } else if (dfast <= bv[r] + DELTA) {
          pd = dfast; pi = code; push = true;
        }
        if (push) {
          if (cd[r][0] > bv[r] + DELTA) { cd[r][0] = pd; cix[r][0] = pi; }
          else if (cd[r][1] > bv[r] + DELTA) { cd[r][1] = pd; cix[r][1] = pi; }
          else {  // overflow: evaluate immediately (always safe)
            const int m = m0 + w * 16 + lk * 4 + r;
            np_eval(&residual[(size_t)m * DIM], &cbqf[(size_t)pi * DIM],
                    t1g[m], cbn_s[pi - cbase], pi, &best64[m]);
          }
        }
      }
    }
  }

  // block-local best across the 16 col-lanes of each row group
  float fb[4] = {bv[0], bv[1], bv[2], bv[3]};
#pragma unroll
  for (int off = 8; off >= 1; off >>= 1)
#pragma unroll
    for (int r = 0; r < 4; ++r)
      fb[r] = fminf(fb[r], __shfl_xor(fb[r], off, 64));

#pragma unroll
  for (int r = 0; r < 4; ++r) {
    const int m = m0 + w * 16 + lk * 4 + r;
    const float* rrow = &residual[(size_t)m * DIM];
    const float t1 = t1g[m];
    if (bv[r] <= fb[r] + DELTA)
      np_eval(rrow, &cbqf[(size_t)bi[r] * DIM], t1, cbn_s[bi[r] - cbase], bi[r], &best64[m]);
    if (cd[r][0] <= fb[r] + DELTA)
      np_eval(rrow, &cbqf[(size_t)cix[r][0] * DIM], t1, cbn_s[cix[r][0] - cbase], cix[r][0], &best64[m]);
    if (cd[r][1] <= fb[r] + DELTA)
      np_eval(rrow, &cbqf[(size_t)cix[r][1] * DIM], t1, cbn_s[cix[r][1] - cbase], cix[r][1], &best64[m]);
  }
}

// ---- update: residual step (np fs), allq, qsum, idx; 16 tokens/block ----
__global__ __launch_bounds__(256) void k_upd(const float* __restrict__ cb,
                                             float* __restrict__ residual,
                                             float* __restrict__ qsum,
                                             float* __restrict__ allq,
                                             float* __restrict__ idxout,
                                             const unsigned long long* __restrict__ best64,
                                             int q) {
  const int m0 = blockIdx.x * 16;
  const int lane = threadIdx.x & 63, w = threadIdx.x >> 6;
  const float* cbq = cb + (size_t)q * NCODE * DIM;
  for (int t = 0; t < 4; ++t) {
    const size_t m = (size_t)m0 + w * 4 + t;
    const int ci = (int)(best64[m] & 0xFFFFFFFFull);
    const float4 cv = *reinterpret_cast<const float4*>(&cbq[(size_t)ci * DIM + lane * 4]);
    const size_t base = m * DIM + lane * 4;
    float4 r = *reinterpret_cast<const float4*>(&residual[base]);
    r.x = fs(r.x, cv.x); r.y = fs(r.y, cv.y); r.z = fs(r.z, cv.z); r.w = fs(r.w, cv.w);
    *reinterpret_cast<float4*>(&residual[base]) = r;
    *reinterpret_cast<float4*>(&allq[((size_t)q * M_TOK + m) * DIM + lane * 4]) = cv;
    if (q == 0) {
      *reinterpret_cast<float4*>(&qsum[base]) = cv;
    } else {
      float4 s4 = *reinterpret_cast<const float4*>(&qsum[base]);
      s4.x += cv.x; s4.y += cv.y; s4.z += cv.z; s4.w += cv.w;
      *reinterpret_cast<float4*>(&qsum[base]) = s4;
    }
    if (lane == 0) idxout[m * NQ + q] = (float)ci;
  }
}

// ---- quantized = relu( qsum @ w_out ), tiled 64x64 ----
__global__ __launch_bounds__(256) void k_gemm_out(const float* __restrict__ A,
                                                  const float* __restrict__ B,
                                                  float* __restrict__ C) {
  __shared__ __align__(16) float As[16][68];
  __shared__ __align__(16) float Bs[16][68];
  const int m0 = blockIdx.x * 64, n0 = blockIdx.y * 64;
  const int tid = threadIdx.x, ty = tid / 16, tx = tid % 16;
  const int at = tid / 4, ad0 = (tid % 4) * 4;
  const int bd = tid / 16, bn = (tid % 16) * 4;
  float acc[4][4] = {};
  for (int kb = 0; kb < DIM; kb += 16) {
    __syncthreads();
    float4 av = *reinterpret_cast<const float4*>(&A[(size_t)(m0 + at) * DIM + kb + ad0]);
    As[ad0 + 0][at] = av.x; As[ad0 + 1][at] = av.y;
    As[ad0 + 2][at] = av.z; As[ad0 + 3][at] = av.w;
    float4 bv = {0.f, 0.f, 0.f, 0.f};
    if (n0 + bn < FEAT)
      bv = *reinterpret_cast<const float4*>(&B[(size_t)(kb + bd) * FEAT + n0 + bn]);
    *reinterpret_cast<float4*>(&Bs[bd][bn]) = bv;
    __syncthreads();
#pragma unroll
    for (int dk = 0; dk < 16; ++dk) {
      float4 a = *reinterpret_cast<const float4*>(&As[dk][ty * 4]);
      float4 b = *reinterpret_cast<const float4*>(&Bs[dk][tx * 4]);
      FMA16();
    }
  }
  const int col = n0 + tx * 4;
  if (col < FEAT) {
#pragma unroll
    for (int i = 0; i < 4; ++i) {
      float4 o;
      o.x = fmaxf(acc[i][0], 0.f); o.y = fmaxf(acc[i][1], 0.f);
      o.z = fmaxf(acc[i][2], 0.f); o.w = fmaxf(acc[i][3], 0.f);
      *reinterpret_cast<float4*>(&C[(size_t)(m0 + ty * 4 + i) * FEAT + col]) = o;
    }
  }
}

extern "C" void kernel_launch(void* const* d_in, const int* in_sizes, int n_in,
                              void* d_out, int out_size, void* d_ws, size_t ws_size,
                              hipStream_t stream) {
  int i_inputs = 0, i_cb = 1, iA = 2, iB = 3;
  {
    int a = -1, b = -1, ii = -1, ic = -1;
    for (int i = 0; i < n_in; ++i) {
      if (in_sizes[i] == M_TOK * FEAT) ii = i;
      else if (in_sizes[i] == NQ * NCODE * DIM) ic = i;
      else if (in_sizes[i] == FEAT * DIM) { if (a < 0) a = i; else b = i; }
    }
    if (ii >= 0 && ic >= 0 && a >= 0 && b >= 0) { i_inputs = ii; i_cb = ic; iA = a; iB = b; }
  }
  const float* inputs = (const float*)d_in[i_inputs];
  const float* cb     = (const float*)d_in[i_cb];
  const float* w_in   = (const float*)d_in[iA];
  const float* w_out  = (const float*)d_in[iB];

  float* out       = (float*)d_out;
  float* quantized = out;                                 // 16384*756
  float* allq      = out + (size_t)M_TOK * FEAT;          // 8*16384*256
  float* idxout    = allq + (size_t)NQ * M_TOK * DIM;     // 16384*8

  // scratch inside the quantized region (rewritten last by k_gemm_out):
  float* residual = quantized;                            // 4,194,304 f
  float* qsum     = residual + (size_t)M_TOK * DIM;       // 4,194,304 f
  float* cbn      = qsum + (size_t)M_TOK * DIM;           // 8,192 f
  float* t1g      = cbn + NQ * NCODE;                     // 16,384 f
  unsigned long long* best64 = (unsigned long long*)(t1g + M_TOK);   // 16,384 u64
  unsigned short* cb16 = (unsigned short*)(best64 + M_TOK);          // 2M bf16 (4MB)
  // total 9,494,528 floats < 12,386,304 available

  k_z16<<<M_TOK / 16, 256, 0, stream>>>(inputs, w_in, residual);
  k_cbnorm<<<NQ * NCODE / 256, 256, 0, stream>>>(cb, cbn);
  k_cb16<<<NQ * NCODE * DIM / 1024, 256, 0, stream>>>(cb, cb16);
  k_t1init<<<M_TOK / 256, 256, 0, stream>>>(residual, t1g, best64);
  for (int q = 0; q < NQ; ++q) {
    k_screen<<<dim3(M_TOK / 64, NCODE / 256), 256, 0, stream>>>(cb16, cb, cbn, residual,
                                                                t1g, best64, q);
    k_upd<<<M_TOK / 16, 256, 0, stream>>>(cb, residual, qsum, allq, idxout, best64, q);
    if (q < NQ - 1)
      k_t1init<<<M_TOK / 256, 256, 0, stream>>>(residual, t1g, best64);
  }
  k_gemm_out<<<dim3(M_TOK / 64, (FEAT + 63) / 64), 256, 0, stream>>>(qsum, w_out, quantized);
}